// Round 17
// baseline (24291.473 us; speedup 1.0000x reference)
//
#include <hip/hip_runtime.h>

#define H 512
#define W4 4
#define RINGN 8
#define NWG 128
#define HS 4          // H / NWG
#define NTH 256

// ---------- helpers ----------
__device__ __forceinline__ float sigf(float x){ return 1.f/(1.f+__expf(-x)); }
__device__ __forceinline__ float tanhft(float x){
  float t = __expf(-2.f*fabsf(x));      // never overflows
  float r = (1.f - t)/(1.f + t);
  return copysignf(r, x);
}
// swizzled LDS element index for column-major weight slices
__device__ __forceinline__ int swz(int dd, int k){
  return (dd << 9) | ((((k >> 2) ^ (dd & 7)) << 2) | (k & 3));
}
__device__ __forceinline__ void st_relax8(unsigned long long* p, unsigned long long v){
  __hip_atomic_store(p, v, __ATOMIC_RELAXED, __HIP_MEMORY_SCOPE_AGENT);
}
__device__ __forceinline__ unsigned long long ld_relax8(const unsigned long long* p){
  return __hip_atomic_load(p, __ATOMIC_RELAXED, __HIP_MEMORY_SCOPE_AGENT);
}
__device__ __forceinline__ unsigned long long pack2(float a, float b){
  return ((unsigned long long)__float_as_uint(b) << 32) | __float_as_uint(a);
}

// ---------- persistent serial lattice scan (tagged-cacheline exchange) ----------
// hline[g]: 128B line = {h[4g..4g+3] (ints 0..3), tag (int 4)}; tag j+1 <=> h(j) ready
// wcline[g]: 128B line = {wc[w][4g+e] at int w*4+e (0..15), tag (int 16)}; tag j <=> wc(j-1)
struct SLds {
  float Wh_l [12*512];
  float Wwh_l[12*512];
  float Wi_l [12*512];
  float Wwi_l[12*512];
  float Ah_l [4*512];
  float Ai_l [4*512];
  float h_l [H];
  float x_l [H];
  float we_l[W4*520];          // wemb(j-1) rows, padded stride
  float wcf [W4*520];          // full wc(j-1), padded stride
  float gh_l[12];
  float wgh_l[12];
  float gx_l[12];
  float awi_l[HS];
  float wgp_l[W4][12];
  float bmi_l[12];
  float bw_l [12];
  float bal_l[HS];
  float hpub[4];
  float wcpub[16];
  float ring_c_l  [RINGN][W4][HS];
  float ring_awh_l[RINGN][W4][HS];
  float c_prev_l[HS];
  int ring_len_l[RINGN][W4];
  int ring_step_l[RINGN];
  int klen_l[W4];
};

__global__ __launch_bounds__(NTH) void lattice_serial(
    const float* __restrict__ xg,  const float* __restrict__ kbe,
    const int*   __restrict__ kblen,
    const float* __restrict__ Wi,  const float* __restrict__ Wh,
    const float* __restrict__ bmi, const float* __restrict__ Ai,
    const float* __restrict__ Ah,  const float* __restrict__ bal,
    const float* __restrict__ Wwi, const float* __restrict__ Wwh,
    const float* __restrict__ bw,
    int* hline, int* wcline,
    float* __restrict__ out, int T)
{
  __shared__ SLds S;
  const int tid  = threadIdx.x;
  const int wg   = blockIdx.x;
  const int base = wg * HS;

  // ---- stage weight column slices (f32, swizzled) ----
  for (int i = tid; i < 12*512; i += NTH){
    int d = i >> 9, k = i & 511;
    size_t gcol = (size_t)(d >> 2)*512 + base + (d & 3);
    S.Wh_l [swz(d,k)] = Wh [(size_t)k*1536 + gcol];
    S.Wwh_l[swz(d,k)] = Wwh[(size_t)k*1536 + gcol];
    S.Wi_l [swz(d,k)] = Wi [(size_t)k*1536 + gcol];
    S.Wwi_l[swz(d,k)] = Wwi[(size_t)k*1536 + gcol];
  }
  for (int i = tid; i < 4*512; i += NTH){
    int c = i >> 9, k = i & 511;
    S.Ah_l[swz(c,k)] = Ah[(size_t)k*512 + base + c];
    S.Ai_l[swz(c,k)] = Ai[(size_t)k*512 + base + c];
  }
  if (tid < 12){
    int gcol = (tid >> 2)*512 + base + (tid & 3);
    S.bmi_l[tid] = bmi[gcol];
    S.bw_l [tid] = bw [gcol];
  }
  if (tid >= 16 && tid < 16+HS) S.bal_l[tid-16] = bal[base + tid - 16];
  for (int i = tid; i < H; i += NTH){ S.h_l[i] = 0.f; S.x_l[i] = 0.f; }
  for (int i = tid; i < W4*520; i += NTH) S.we_l[i] = 0.f;
  for (int i = tid; i < RINGN*W4*HS; i += NTH){
    ((float*)S.ring_c_l)[i]   = 0.f;
    ((float*)S.ring_awh_l)[i] = 0.f;
  }
  if (tid < RINGN) S.ring_step_l[tid] = -2*RINGN;
  if (tid < RINGN*W4) ((int*)S.ring_len_l)[tid] = 0;
  if (tid < HS) S.c_prev_l[tid] = 0.f;
  __syncthreads();

  for (int j = 0; j < T; ++j){
    // ---- stage x(j), wemb(j-1), klen(j-1) (h-independent) ----
    {
      float xv0 = xg[(size_t)j*H + tid];
      float xv1 = xg[(size_t)j*H + NTH + tid];
      S.x_l[tid] = xv0; S.x_l[NTH + tid] = xv1;
      if (j > 0){
        #pragma unroll
        for (int r = 0; r < 8; ++r){
          int i = r*NTH + tid;
          S.we_l[(i >> 9)*520 + (i & 511)] = kbe[(size_t)(j-1)*(W4*H) + i];
        }
        if (tid < W4) S.klen_l[tid] = kblen[(size_t)(j-1)*W4 + tid];
      }
    }
    __syncthreads();

    // ---- PROJ (h-independent): gx(j)=x·Wi, awi(j)=x·Ai, wgp(j-1)=wemb·Wwi ----
    {
      const int sub = tid & 7;
      #pragma unroll
      for (int p = 0; p < 2; ++p){
        int dotid = p*32 + (tid >> 3);
        const float* Apt; const float* Wb; int row;
        if (dotid < 12)      { Apt = S.x_l; Wb = S.Wi_l; row = dotid; }
        else if (dotid < 16) { Apt = S.x_l; Wb = S.Ai_l; row = dotid - 12; }
        else { int q = dotid - 16; Apt = &S.we_l[(q/12)*520]; Wb = S.Wwi_l; row = q % 12; }
        float acc = 0.f;
        #pragma unroll
        for (int i2 = 0; i2 < 16; ++i2){
          int cch = (i2 << 3) | sub;
          const float4 a4 = *(const float4*)&Apt[cch << 2];
          const float4 w4 = *(const float4*)&Wb[(row << 9) + ((cch ^ (row & 7)) << 2)];
          acc = fmaf(a4.x, w4.x, acc);
          acc = fmaf(a4.y, w4.y, acc);
          acc = fmaf(a4.z, w4.z, acc);
          acc = fmaf(a4.w, w4.w, acc);
        }
        acc += __shfl_xor(acc, 1); acc += __shfl_xor(acc, 2); acc += __shfl_xor(acc, 4);
        if (sub == 0){
          if (dotid < 12)      S.gx_l[dotid]      = acc + S.bmi_l[dotid];
          else if (dotid < 16) S.awi_l[dotid-12]  = acc + S.bal_l[dotid-12];
          else { int q = dotid-16; S.wgp_l[q/12][q%12] = acc + S.bw_l[q%12]; }
        }
      }
    }

    // ---- poll+read h(j-1): tag >= j on each of 128 h-lines (parallel) ----
    if (j > 0){
      int g = tid >> 1, half = tid & 1;
      const int* line = hline + g*32;
      while (__hip_atomic_load(&line[4], __ATOMIC_ACQUIRE, __HIP_MEMORY_SCOPE_AGENT) < j)
        __builtin_amdgcn_s_sleep(1);
      unsigned long long q = ld_relax8((const unsigned long long*)line + half);
      ((unsigned long long*)S.h_l)[g*2 + half] = q;
    }
    __syncthreads();

    // ---- Phase A1: wgh(j-1) = h·Wwh cols (12 dots, tid<96) ----
    if (j > 0 && tid < 96){
      const int sub = tid & 7;
      int d = tid >> 3;
      float acc = 0.f;
      #pragma unroll
      for (int i2 = 0; i2 < 16; ++i2){
        int cch = (i2 << 3) | sub;
        const float4 hv  = *(const float4*)&S.h_l[cch << 2];
        const float4 wv4 = *(const float4*)&S.Wwh_l[(d << 9) + ((cch ^ (d & 7)) << 2)];
        acc = fmaf(hv.x, wv4.x, acc);
        acc = fmaf(hv.y, wv4.y, acc);
        acc = fmaf(hv.z, wv4.z, acc);
        acc = fmaf(hv.w, wv4.w, acc);
      }
      acc += __shfl_xor(acc, 1); acc += __shfl_xor(acc, 2); acc += __shfl_xor(acc, 4);
      if (sub == 0) S.wgh_l[d] = acc;
    }
    __syncthreads();

    if (j > 0){
      // ---- wc(j-1) local slice into LDS for the publisher ----
      if (tid < W4*HS){
        int w = tid >> 2, e = tid & 3;
        float fr = S.wgp_l[w][e]   + S.wgh_l[e];
        float ir = S.wgp_l[w][4+e] + S.wgh_l[4+e];
        float gr = S.wgp_l[w][8+e] + S.wgh_l[8+e];
        S.wcpub[w*4 + e] = sigf(fr)*S.c_prev_l[e] + sigf(ir)*tanhft(gr);
      }
      __syncthreads();
    }

    // ---- publisher (wave 3) releases wc-line; waves 0-1 compute gh concurrently ----
    if (j > 0 && tid == 192){
      unsigned long long* L = (unsigned long long*)(wcline + wg*32);
      #pragma unroll
      for (int m = 0; m < 8; ++m)
        st_relax8(&L[m], pack2(S.wcpub[2*m], S.wcpub[2*m+1]));
      __hip_atomic_store(&wcline[wg*32 + 16], j, __ATOMIC_RELEASE, __HIP_MEMORY_SCOPE_AGENT);
    }

    // ---- Phase A2: gh(j) = h·Wh cols (12 dots, tid<96) ----
    if (tid < 96){
      const int sub = tid & 7;
      int d = tid >> 3;
      float acc = 0.f;
      #pragma unroll
      for (int i2 = 0; i2 < 16; ++i2){
        int cch = (i2 << 3) | sub;
        const float4 hv  = *(const float4*)&S.h_l[cch << 2];
        const float4 wv4 = *(const float4*)&S.Wh_l[(d << 9) + ((cch ^ (d & 7)) << 2)];
        acc = fmaf(hv.x, wv4.x, acc);
        acc = fmaf(hv.y, wv4.y, acc);
        acc = fmaf(hv.z, wv4.z, acc);
        acc = fmaf(hv.w, wv4.w, acc);
      }
      acc += __shfl_xor(acc, 1); acc += __shfl_xor(acc, 2); acc += __shfl_xor(acc, 4);
      if (sub == 0) S.gh_l[d] = acc;
    }

    // ---- poll+read full wc(j-1): tag >= j on each of 128 wc-lines ----
    if (j > 0){
      int g = tid >> 1, half = tid & 1;
      const int* line = wcline + g*32;
      while (__hip_atomic_load(&line[16], __ATOMIC_ACQUIRE, __HIP_MEMORY_SCOPE_AGENT) < j)
        __builtin_amdgcn_s_sleep(1);
      const unsigned long long* L = (const unsigned long long*)line;
      #pragma unroll
      for (int m = 0; m < 4; ++m){
        unsigned long long q = ld_relax8(&L[half*4 + m]);
        int idx = half*8 + 2*m;          // even f-index in [0,16)
        int w = idx >> 2, e = idx & 3;   // idx+1 stays in same w (e<3)
        *(unsigned long long*)&S.wcf[w*520 + 4*g + e] = q;
      }
    }
    __syncthreads();

    // ---- Phase B: awh(j-1) slice = wc·Ah cols; ring update ----
    if (j > 0){
      const int s = (j-1) & 7;
      if (tid < 128){
        int dt = tid >> 3, sub = tid & 7;
        int w = dt >> 2, c = dt & 3;
        float acc = 0.f;
        #pragma unroll
        for (int i2 = 0; i2 < 16; ++i2){
          int cch = (i2 << 3) | sub;
          const float4 wv4 = *(const float4*)&S.wcf[w*520 + (cch << 2)];
          const float4 av  = *(const float4*)&S.Ah_l[(c << 9) + ((cch ^ (c & 7)) << 2)];
          acc = fmaf(wv4.x, av.x, acc);
          acc = fmaf(wv4.y, av.y, acc);
          acc = fmaf(wv4.z, av.z, acc);
          acc = fmaf(wv4.w, av.w, acc);
        }
        acc += __shfl_xor(acc, 1); acc += __shfl_xor(acc, 2); acc += __shfl_xor(acc, 4);
        if (sub == 0) S.ring_awh_l[s][w][c] = acc;
      }
      if (tid < W4*HS){ int w = tid >> 2, e = tid & 3; S.ring_c_l[s][w][e] = S.wcf[w*520 + base + e]; }
      if (tid < W4) S.ring_len_l[s][tid] = S.klen_l[tid];
      if (tid == 0) S.ring_step_l[s] = j-1;
    }
    __syncthreads();

    // ---- Phase C: part2(j) — fully local; stage h(j) for publisher ----
    if (tid < 128){
      int entry = tid & 31, e = tid >> 5;
      int s = entry >> 2, w = entry & 3;
      bool msk = (S.ring_step_l[s] + S.ring_len_l[s][w] - 1 == j);
      float aw = S.awi_l[e] + S.ring_awh_l[s][w][e];
      float ev  = msk ? __expf(sigf(aw)) : 0.f;
      float ecv = msk ? ev * S.ring_c_l[s][w][e] : 0.f;
      #pragma unroll
      for (int m = 1; m < 32; m <<= 1){
        ev  += __shfl_xor(ev,  m);
        ecv += __shfl_xor(ecv, m);
      }
      int anym = __any((int)msk);
      float ir  = S.gx_l[e]   + S.gh_l[e];
      float orr = S.gx_l[4+e] + S.gh_l[4+e];
      float gr  = S.gx_l[8+e] + S.gh_l[8+e];
      float i_g = sigf(ir), o_g = tanhft(orr), g_g = sigf(gr);
      float e_i = __expf(i_g);
      float c_new;
      if (anym) c_new = (e_i*g_g + ecv) / (e_i + ev);
      else      c_new = (1.f - i_g)*S.c_prev_l[e] + i_g*g_g;
      float h_new = o_g * tanhft(c_new);
      if (entry == 0){
        S.hpub[e] = h_new;
        out[(size_t)j*H + base + e]               = h_new;   // f32 store
        out[(size_t)T*H + (size_t)j*H + base + e] = c_new;   // f32 store
        S.c_prev_l[e] = c_new;
      }
    }
    __syncthreads();

    // ---- publisher (wave 3) releases h-line with tag j+1 ----
    if (tid == 192){
      unsigned long long* L = (unsigned long long*)(hline + wg*32);
      st_relax8(&L[0], pack2(S.hpub[0], S.hpub[1]));
      st_relax8(&L[1], pack2(S.hpub[2], S.hpub[3]));
      __hip_atomic_store(&hline[wg*32 + 4], j+1, __ATOMIC_RELEASE, __HIP_MEMORY_SCOPE_AGENT);
    }
  }
}

// ---------- launcher ----------
extern "C" void kernel_launch(void* const* d_in, const int* in_sizes, int n_in,
                              void* d_out, int out_size, void* d_ws, size_t ws_size,
                              hipStream_t stream)
{
  const float* x    = (const float*)d_in[0];
  const float* kbe  = (const float*)d_in[1];
  const int*   kblen= (const int*)d_in[2];
  const float* Wi   = (const float*)d_in[3];
  const float* Wh   = (const float*)d_in[4];
  const float* bmi  = (const float*)d_in[5];
  const float* Ai   = (const float*)d_in[6];
  const float* Ah   = (const float*)d_in[7];
  const float* bal  = (const float*)d_in[8];
  const float* Wwi  = (const float*)d_in[9];
  const float* Wwh  = (const float*)d_in[10];
  const float* bw   = (const float*)d_in[11];
  const int T = in_sizes[0] / H;     // 1024
  float* out = (float*)d_out;        // reference output dtype = float32

  // workspace: hline[128*32 ints] | wcline[128*32 ints]  (32 KB of tagged lines)
  int* hline  = (int*)d_ws;
  int* wcline = hline + NWG*32;

  (void)hipMemsetAsync(hline, 0, (size_t)2*NWG*32*sizeof(int), stream);

  lattice_serial<<<NWG, NTH, 0, stream>>>(x, kbe, kblen, Wi, Wh, bmi, Ai, Ah, bal,
                                          Wwi, Wwh, bw, hline, wcline, out, T);
}

// Round 18
// 13402.370 us; speedup vs baseline: 1.8125x; 1.8125x over previous
//
#include <hip/hip_runtime.h>

#define H 512
#define W4 4
#define RINGN 8
#define NWG 64
#define HS 8          // H / NWG
#define NTH 256

// ---------- helpers ----------
__device__ __forceinline__ float sigf(float x){ return 1.f/(1.f+__expf(-x)); }
__device__ __forceinline__ float tanhft(float x){
  float t = __expf(-2.f*fabsf(x));      // never overflows
  float r = (1.f - t)/(1.f + t);
  return copysignf(r, x);
}
// swizzled LDS element index for column-major weight slices
__device__ __forceinline__ int swz(int dd, int k){
  return (dd << 9) | ((((k >> 2) ^ (dd & 7)) << 2) | (k & 3));
}
__device__ __forceinline__ void st_relax(float* p, float v){
  __hip_atomic_store(p, v, __ATOMIC_RELAXED, __HIP_MEMORY_SCOPE_AGENT);
}
__device__ __forceinline__ unsigned long long ld_relax8(const unsigned long long* p){
  return __hip_atomic_load(p, __ATOMIC_RELAXED, __HIP_MEMORY_SCOPE_AGENT);
}
// flat central-counter barrier, split arrive/detect (monotone per-step counters)
__device__ __forceinline__ void arrive(int* c){
  __hip_atomic_fetch_add(c, 1, __ATOMIC_ACQ_REL, __HIP_MEMORY_SCOPE_AGENT);
}
__device__ __forceinline__ void detect(const int* c){
  while (__hip_atomic_load(c, __ATOMIC_ACQUIRE, __HIP_MEMORY_SCOPE_AGENT) < NWG)
    __builtin_amdgcn_s_sleep(2);
}

// ---------- transpose: in[512][1536] -> out[1536][512] (both sides coalesced) ----------
__global__ __launch_bounds__(256) void transpose_k(const float* __restrict__ in,
                                                   float* __restrict__ out){
  __shared__ float tile[32][33];
  const int bx = blockIdx.x, by = blockIdx.y;
  const int tx = threadIdx.x & 31, ty = threadIdx.x >> 5;
  #pragma unroll
  for (int r = 0; r < 4; ++r)
    tile[ty + r*8][tx] = in[(size_t)(by*32 + ty + r*8)*1536 + bx*32 + tx];
  __syncthreads();
  #pragma unroll
  for (int r = 0; r < 4; ++r)
    out[(size_t)(bx*32 + ty + r*8)*512 + by*32 + tx] = tile[tx][ty + r*8];
}

// ---------- persistent serial lattice scan (NWG=64, HS=8) ----------
struct SLds {
  float Wh_l [24*512];
  float Wwh_l[24*512];
  float Ah_l [8*512];
  float Ai_l [8*512];
  float h_l [H];
  float x_l [H];
  float we_l[W4*520];          // wemb(j-1) rows, padded stride
  float wcf [W4*520];          // full wc(j-1), padded stride
  float gh_l[24];
  float wgh_l[24];
  float gx_l[24];
  float awi_l[HS];
  float wgp_l[W4][24];
  float bmi_l[24];
  float bw_l [24];
  float bal_l[HS];
  float ring_c_l  [RINGN][W4][HS];
  float ring_awh_l[RINGN][W4][HS];
  float c_prev_l[HS];
  int ring_len_l[RINGN][W4];
  int ring_step_l[RINGN];
  int klen_l[W4];
};

__global__ __launch_bounds__(NTH) void lattice_serial(
    const float* __restrict__ xg,  const float* __restrict__ kbe,
    const int*   __restrict__ kblen,
    const float* __restrict__ WiT, const float* __restrict__ Wh,
    const float* __restrict__ bmi, const float* __restrict__ Ai,
    const float* __restrict__ Ah,  const float* __restrict__ bal,
    const float* __restrict__ WwiT,const float* __restrict__ Wwh,
    const float* __restrict__ bw,
    float* hbuf, float* wcbuf, int* cnt,
    float* __restrict__ out, int T)
{
  __shared__ SLds S;
  const int tid  = threadIdx.x;
  const int wg   = blockIdx.x;
  const int base = wg * HS;

  // ---- stage weight column slices (f32, swizzled): Wh, Wwh, Ah, Ai ----
  for (int i = tid; i < 24*512; i += NTH){
    int d = i >> 9, k = i & 511;
    size_t gcol = (size_t)(d >> 3)*512 + base + (d & 7);
    S.Wh_l [swz(d,k)] = Wh [(size_t)k*1536 + gcol];
    S.Wwh_l[swz(d,k)] = Wwh[(size_t)k*1536 + gcol];
  }
  for (int i = tid; i < 8*512; i += NTH){
    int c = i >> 9, k = i & 511;
    S.Ah_l[swz(c,k)] = Ah[(size_t)k*512 + base + c];
    S.Ai_l[swz(c,k)] = Ai[(size_t)k*512 + base + c];
  }
  if (tid < 24){
    int gcol = (tid >> 3)*512 + base + (tid & 7);
    S.bmi_l[tid] = bmi[gcol];
    S.bw_l [tid] = bw [gcol];
  }
  if (tid >= 32 && tid < 32+HS) S.bal_l[tid-32] = bal[base + tid - 32];
  for (int i = tid; i < H; i += NTH){ S.h_l[i] = 0.f; S.x_l[i] = 0.f; }
  for (int i = tid; i < W4*520; i += NTH) S.we_l[i] = 0.f;
  for (int i = tid; i < RINGN*W4*HS; i += NTH){
    ((float*)S.ring_c_l)[i]   = 0.f;
    ((float*)S.ring_awh_l)[i] = 0.f;
  }
  if (tid < RINGN) S.ring_step_l[tid] = -2*RINGN;
  if (tid < RINGN*W4) ((int*)S.ring_len_l)[tid] = 0;
  if (tid < HS) S.c_prev_l[tid] = 0.f;
  __syncthreads();

  for (int j = 0; j < T; ++j){
    // ---- stage x(j), wemb(j-1), klen(j-1) (h-independent) ----
    {
      float xv0 = xg[(size_t)j*H + tid];
      float xv1 = xg[(size_t)j*H + NTH + tid];
      S.x_l[tid] = xv0; S.x_l[NTH + tid] = xv1;
      if (j > 0){
        #pragma unroll
        for (int r = 0; r < 8; ++r){
          int i = r*NTH + tid;
          S.we_l[(i >> 9)*520 + (i & 511)] = kbe[(size_t)(j-1)*(W4*H) + i];
        }
        if (tid < W4) S.klen_l[tid] = kblen[(size_t)(j-1)*W4 + tid];
      }
    }
    __syncthreads();

    // ---- PROJ (h-independent): gx=x·WiT(global), awi=x·Ai(LDS), wgp=wemb·WwiT(global)
    //      128 dots, 4 passes of 32 ----
    {
      const int sub = tid & 7;
      #pragma unroll
      for (int p = 0; p < 4; ++p){
        int dotid = p*32 + (tid >> 3);
        float acc = 0.f;
        if (dotid < 24){                       // gx: coalesced global WiT rows
          int col = (dotid >> 3)*512 + base + (dotid & 7);
          const float* Wp = WiT + (size_t)col*512;
          #pragma unroll
          for (int i2 = 0; i2 < 16; ++i2){
            int cch = (i2 << 3) | sub;
            const float4 a4 = *(const float4*)&S.x_l[cch << 2];
            const float4 w4 = *(const float4*)&Wp[cch << 2];
            acc = fmaf(a4.x, w4.x, acc); acc = fmaf(a4.y, w4.y, acc);
            acc = fmaf(a4.z, w4.z, acc); acc = fmaf(a4.w, w4.w, acc);
          }
        } else if (dotid < 32){                // awi: LDS Ai
          int e = dotid - 24;
          #pragma unroll
          for (int i2 = 0; i2 < 16; ++i2){
            int cch = (i2 << 3) | sub;
            const float4 a4 = *(const float4*)&S.x_l[cch << 2];
            const float4 w4 = *(const float4*)&S.Ai_l[(e << 9) + ((cch ^ (e & 7)) << 2)];
            acc = fmaf(a4.x, w4.x, acc); acc = fmaf(a4.y, w4.y, acc);
            acc = fmaf(a4.z, w4.z, acc); acc = fmaf(a4.w, w4.w, acc);
          }
        } else {                               // wgp: coalesced global WwiT rows
          int q = dotid - 32, w = q / 24, d = q % 24;
          int col = (d >> 3)*512 + base + (d & 7);
          const float* Wp = WwiT + (size_t)col*512;
          const float* vec = &S.we_l[w*520];
          #pragma unroll
          for (int i2 = 0; i2 < 16; ++i2){
            int cch = (i2 << 3) | sub;
            const float4 a4 = *(const float4*)&vec[cch << 2];
            const float4 w4 = *(const float4*)&Wp[cch << 2];
            acc = fmaf(a4.x, w4.x, acc); acc = fmaf(a4.y, w4.y, acc);
            acc = fmaf(a4.z, w4.z, acc); acc = fmaf(a4.w, w4.w, acc);
          }
        }
        acc += __shfl_xor(acc, 1); acc += __shfl_xor(acc, 2); acc += __shfl_xor(acc, 4);
        if (sub == 0){
          if (dotid < 24)      S.gx_l[dotid]     = acc + S.bmi_l[dotid];
          else if (dotid < 32) S.awi_l[dotid-24] = acc + S.bal_l[dotid-24];
          else { int q = dotid-32; S.wgp_l[q/24][q%24] = acc + S.bw_l[q%24]; }
        }
      }
    }

    // ---- detect h(j-1) published (C-counter of step j-1); read it ----
    if (j > 0){
      if (tid == 192) detect(&cnt[2*j - 1]);
      __syncthreads();
      ((unsigned long long*)S.h_l)[tid] = ld_relax8((const unsigned long long*)hbuf + tid);
    }
    __syncthreads();

    // ---- Phase A1: wgh(j-1) = h·Wwh cols (24 dots, tid<192) ----
    if (j > 0 && tid < 192){
      const int sub = tid & 7;
      int d = tid >> 3;
      float acc = 0.f;
      #pragma unroll
      for (int i2 = 0; i2 < 16; ++i2){
        int cch = (i2 << 3) | sub;
        const float4 hv  = *(const float4*)&S.h_l[cch << 2];
        const float4 wv4 = *(const float4*)&S.Wwh_l[(d << 9) + ((cch ^ (d & 7)) << 2)];
        acc = fmaf(hv.x, wv4.x, acc); acc = fmaf(hv.y, wv4.y, acc);
        acc = fmaf(hv.z, wv4.z, acc); acc = fmaf(hv.w, wv4.w, acc);
      }
      acc += __shfl_xor(acc, 1); acc += __shfl_xor(acc, 2); acc += __shfl_xor(acc, 4);
      if (sub == 0) S.wgh_l[d] = acc;
    }
    __syncthreads();

    if (j > 0){
      // ---- wc(j-1) local slice, publish; flat-arrive (A-counter, step j) ----
      if (tid < W4*HS){
        int w = tid >> 3, e = tid & 7;
        float fr = S.wgp_l[w][e]    + S.wgh_l[e];
        float ir = S.wgp_l[w][8+e]  + S.wgh_l[8+e];
        float gr = S.wgp_l[w][16+e] + S.wgh_l[16+e];
        float wcv = sigf(fr)*S.c_prev_l[e] + sigf(ir)*tanhft(gr);
        st_relax(&wcbuf[w*H + base + e], wcv);
      }
      __syncthreads();               // drain wc stores
      if (tid == 192) arrive(&cnt[2*j]);
    }

    // ---- Phase A2: gh(j) = h·Wh cols (24 dots, tid<192) — hides A-barrier ----
    if (tid < 192){
      const int sub = tid & 7;
      int d = tid >> 3;
      float acc = 0.f;
      #pragma unroll
      for (int i2 = 0; i2 < 16; ++i2){
        int cch = (i2 << 3) | sub;
        const float4 hv  = *(const float4*)&S.h_l[cch << 2];
        const float4 wv4 = *(const float4*)&S.Wh_l[(d << 9) + ((cch ^ (d & 7)) << 2)];
        acc = fmaf(hv.x, wv4.x, acc); acc = fmaf(hv.y, wv4.y, acc);
        acc = fmaf(hv.z, wv4.z, acc); acc = fmaf(hv.w, wv4.w, acc);
      }
      acc += __shfl_xor(acc, 1); acc += __shfl_xor(acc, 2); acc += __shfl_xor(acc, 4);
      if (sub == 0) S.gh_l[d] = acc;
    }

    // ---- detect A-counter; read full wc(j-1) ----
    if (j > 0){
      if (tid == 192) detect(&cnt[2*j]);
      __syncthreads();
      const unsigned long long* wb = (const unsigned long long*)wcbuf;
      #pragma unroll
      for (int r = 0; r < 4; ++r){
        int i = r*NTH + tid;                       // pair index 0..1023
        unsigned long long v = ld_relax8(&wb[i]);
        int w = i >> 8, k = (i & 255) << 1;
        *(unsigned long long*)&S.wcf[w*520 + k] = v;
      }
    }
    __syncthreads();

    // ---- Phase B: awh(j-1) slice = wc·Ah cols (32 dots, all 256); ring update ----
    if (j > 0){
      const int s = (j-1) & 7;
      {
        int dt = tid >> 3, sub = tid & 7;
        int w = dt >> 3, c = dt & 7;
        float acc = 0.f;
        #pragma unroll
        for (int i2 = 0; i2 < 16; ++i2){
          int cch = (i2 << 3) | sub;
          const float4 wv4 = *(const float4*)&S.wcf[w*520 + (cch << 2)];
          const float4 av  = *(const float4*)&S.Ah_l[(c << 9) + ((cch ^ (c & 7)) << 2)];
          acc = fmaf(wv4.x, av.x, acc); acc = fmaf(wv4.y, av.y, acc);
          acc = fmaf(wv4.z, av.z, acc); acc = fmaf(wv4.w, av.w, acc);
        }
        acc += __shfl_xor(acc, 1); acc += __shfl_xor(acc, 2); acc += __shfl_xor(acc, 4);
        if (sub == 0) S.ring_awh_l[s][w][c] = acc;
      }
      if (tid < W4*HS){ int w = tid >> 3, e = tid & 7; S.ring_c_l[s][w][e] = S.wcf[w*520 + base + e]; }
      if (tid < W4) S.ring_len_l[s][tid] = S.klen_l[tid];
      if (tid == 0) S.ring_step_l[s] = j-1;
    }
    __syncthreads();

    // ---- Phase C: part2(j) — 32 entries x 8 elems = 256 threads ----
    {
      int entry = tid & 31, e = tid >> 5;
      int s = entry >> 2, w = entry & 3;
      bool msk = (S.ring_step_l[s] + S.ring_len_l[s][w] - 1 == j);
      float aw = S.awi_l[e] + S.ring_awh_l[s][w][e];
      float ev  = msk ? __expf(sigf(aw)) : 0.f;
      float ecv = msk ? ev * S.ring_c_l[s][w][e] : 0.f;
      #pragma unroll
      for (int m = 1; m < 32; m <<= 1){
        ev  += __shfl_xor(ev,  m);
        ecv += __shfl_xor(ecv, m);
      }
      int anym = __any((int)msk);
      float ir  = S.gx_l[e]    + S.gh_l[e];
      float orr = S.gx_l[8+e]  + S.gh_l[8+e];
      float gr  = S.gx_l[16+e] + S.gh_l[16+e];
      float i_g = sigf(ir), o_g = tanhft(orr), g_g = sigf(gr);
      float e_i = __expf(i_g);
      float c_new;
      if (anym) c_new = (e_i*g_g + ecv) / (e_i + ev);
      else      c_new = (1.f - i_g)*S.c_prev_l[e] + i_g*g_g;
      float h_new = o_g * tanhft(c_new);
      if (entry == 0){
        st_relax(&hbuf[base+e], h_new);
        out[(size_t)j*H + base + e]               = h_new;   // f32 store
        out[(size_t)T*H + (size_t)j*H + base + e] = c_new;   // f32 store
        S.c_prev_l[e] = c_new;
      }
    }
    __syncthreads();                 // drain h stores
    if (tid == 192) arrive(&cnt[2*j + 1]);   // C-counter of step j; detected next step
  }
}

// ---------- launcher ----------
extern "C" void kernel_launch(void* const* d_in, const int* in_sizes, int n_in,
                              void* d_out, int out_size, void* d_ws, size_t ws_size,
                              hipStream_t stream)
{
  const float* x    = (const float*)d_in[0];
  const float* kbe  = (const float*)d_in[1];
  const int*   kblen= (const int*)d_in[2];
  const float* Wi   = (const float*)d_in[3];
  const float* Wh   = (const float*)d_in[4];
  const float* bmi  = (const float*)d_in[5];
  const float* Ai   = (const float*)d_in[6];
  const float* Ah   = (const float*)d_in[7];
  const float* bal  = (const float*)d_in[8];
  const float* Wwi  = (const float*)d_in[9];
  const float* Wwh  = (const float*)d_in[10];
  const float* bw   = (const float*)d_in[11];
  const int T = in_sizes[0] / H;     // 1024
  float* out = (float*)d_out;        // reference output dtype = float32

  // workspace: WiT[1536*512] | WwiT[1536*512] | hbuf[512] | wcbuf[2048] | cnt[2*T]
  float* ws    = (float*)d_ws;
  float* WiT   = ws;
  float* WwiT  = WiT + (size_t)1536*512;
  float* hbuf  = WwiT + (size_t)1536*512;
  float* wcbuf = hbuf + 512;
  int*   cnt   = (int*)(wcbuf + 2048);

  (void)hipMemsetAsync(cnt, 0, (size_t)2*T*sizeof(int), stream);

  transpose_k<<<dim3(48,16), 256, 0, stream>>>(Wi,  WiT);
  transpose_k<<<dim3(48,16), 256, 0, stream>>>(Wwi, WwiT);

  lattice_serial<<<NWG, NTH, 0, stream>>>(x, kbe, kblen, WiT, Wh, bmi, Ai, Ah, bal,
                                          WwiT, Wwh, bw, hbuf, wcbuf, cnt, out, T);
}

// Round 19
// 12927.209 us; speedup vs baseline: 1.8791x; 1.0368x over previous
//
#include <hip/hip_runtime.h>

#define H 512
#define W4 4
#define RINGN 8
#define NWG 64
#define HS 8          // H / NWG
#define NTH 256

// ---------- helpers ----------
__device__ __forceinline__ float sigf(float x){ return 1.f/(1.f+__expf(-x)); }
__device__ __forceinline__ float tanhft(float x){
  float t = __expf(-2.f*fabsf(x));      // never overflows
  float r = (1.f - t)/(1.f + t);
  return copysignf(r, x);
}
// swizzled LDS element index for column-major weight slices
__device__ __forceinline__ int swz(int dd, int k){
  return (dd << 9) | ((((k >> 2) ^ (dd & 7)) << 2) | (k & 3));
}
__device__ __forceinline__ void st_relax(float* p, float v){
  __hip_atomic_store(p, v, __ATOMIC_RELAXED, __HIP_MEMORY_SCOPE_AGENT);
}
__device__ __forceinline__ unsigned long long ld_relax8(const unsigned long long* p){
  return __hip_atomic_load(p, __ATOMIC_RELAXED, __HIP_MEMORY_SCOPE_AGENT);
}
// flat central-counter barrier, split arrive/detect (monotone per-step counters).
// arrive keeps ACQ_REL (release: data visible at IC before counter bump).
// detect polls RELAXED (no per-iteration L2 invalidation) with a periodic
// ACQUIRE fallback in case relaxed agent loads can be served stale.
__device__ __forceinline__ void arrive(int* c){
  __hip_atomic_fetch_add(c, 1, __ATOMIC_ACQ_REL, __HIP_MEMORY_SCOPE_AGENT);
}
__device__ __forceinline__ void detect(const int* c){
  int it = 0;
  while (1){
    int v = ((++it & 255) == 0)
      ? __hip_atomic_load(c, __ATOMIC_ACQUIRE, __HIP_MEMORY_SCOPE_AGENT)
      : __hip_atomic_load(c, __ATOMIC_RELAXED, __HIP_MEMORY_SCOPE_AGENT);
    if (v >= NWG) break;
    __builtin_amdgcn_s_sleep(1);
  }
}

// ---------- transpose: in[512][1536] -> out[1536][512] (both sides coalesced) ----------
__global__ __launch_bounds__(256) void transpose_k(const float* __restrict__ in,
                                                   float* __restrict__ out){
  __shared__ float tile[32][33];
  const int bx = blockIdx.x, by = blockIdx.y;
  const int tx = threadIdx.x & 31, ty = threadIdx.x >> 5;
  #pragma unroll
  for (int r = 0; r < 4; ++r)
    tile[ty + r*8][tx] = in[(size_t)(by*32 + ty + r*8)*1536 + bx*32 + tx];
  __syncthreads();
  #pragma unroll
  for (int r = 0; r < 4; ++r)
    out[(size_t)(bx*32 + ty + r*8)*512 + by*32 + tx] = tile[tx][ty + r*8];
}

// ---------- persistent serial lattice scan (NWG=64, HS=8) ----------
struct SLds {
  float Wh_l [24*512];
  float Wwh_l[24*512];
  float Ah_l [8*512];
  float Ai_l [8*512];
  float h_l [H];
  float x_l [H];
  float we_l[W4*520];          // wemb(j-1) rows, padded stride
  float wcf [W4*520];          // full wc(j-1), padded stride
  float gh_l[24];
  float wgh_l[24];
  float gx_l[24];
  float awi_l[HS];
  float wgp_l[W4][24];
  float bmi_l[24];
  float bw_l [24];
  float bal_l[HS];
  float ring_c_l  [RINGN][W4][HS];
  float ring_awh_l[RINGN][W4][HS];
  float c_prev_l[HS];
  int ring_len_l[RINGN][W4];
  int ring_step_l[RINGN];
  int klen_l[W4];
};

__global__ __launch_bounds__(NTH) void lattice_serial(
    const float* __restrict__ xg,  const float* __restrict__ kbe,
    const int*   __restrict__ kblen,
    const float* __restrict__ WiT, const float* __restrict__ Wh,
    const float* __restrict__ bmi, const float* __restrict__ Ai,
    const float* __restrict__ Ah,  const float* __restrict__ bal,
    const float* __restrict__ WwiT,const float* __restrict__ Wwh,
    const float* __restrict__ bw,
    float* hbuf, float* wcbuf, int* cnt,
    float* __restrict__ out, int T)
{
  __shared__ SLds S;
  const int tid  = threadIdx.x;
  const int wg   = blockIdx.x;
  const int base = wg * HS;

  // ---- stage weight column slices (f32, swizzled): Wh, Wwh, Ah, Ai ----
  for (int i = tid; i < 24*512; i += NTH){
    int d = i >> 9, k = i & 511;
    size_t gcol = (size_t)(d >> 3)*512 + base + (d & 7);
    S.Wh_l [swz(d,k)] = Wh [(size_t)k*1536 + gcol];
    S.Wwh_l[swz(d,k)] = Wwh[(size_t)k*1536 + gcol];
  }
  for (int i = tid; i < 8*512; i += NTH){
    int c = i >> 9, k = i & 511;
    S.Ah_l[swz(c,k)] = Ah[(size_t)k*512 + base + c];
    S.Ai_l[swz(c,k)] = Ai[(size_t)k*512 + base + c];
  }
  if (tid < 24){
    int gcol = (tid >> 3)*512 + base + (tid & 7);
    S.bmi_l[tid] = bmi[gcol];
    S.bw_l [tid] = bw [gcol];
  }
  if (tid >= 32 && tid < 32+HS) S.bal_l[tid-32] = bal[base + tid - 32];
  for (int i = tid; i < H; i += NTH){ S.h_l[i] = 0.f; S.x_l[i] = 0.f; }
  for (int i = tid; i < W4*520; i += NTH) S.we_l[i] = 0.f;
  for (int i = tid; i < RINGN*W4*HS; i += NTH){
    ((float*)S.ring_c_l)[i]   = 0.f;
    ((float*)S.ring_awh_l)[i] = 0.f;
  }
  if (tid < RINGN) S.ring_step_l[tid] = -2*RINGN;
  if (tid < RINGN*W4) ((int*)S.ring_len_l)[tid] = 0;
  if (tid < HS) S.c_prev_l[tid] = 0.f;
  __syncthreads();

  for (int j = 0; j < T; ++j){
    // ---- stage x(j), wemb(j-1), klen(j-1) (h-independent) ----
    {
      float xv0 = xg[(size_t)j*H + tid];
      float xv1 = xg[(size_t)j*H + NTH + tid];
      S.x_l[tid] = xv0; S.x_l[NTH + tid] = xv1;
      if (j > 0){
        #pragma unroll
        for (int r = 0; r < 8; ++r){
          int i = r*NTH + tid;
          S.we_l[(i >> 9)*520 + (i & 511)] = kbe[(size_t)(j-1)*(W4*H) + i];
        }
        if (tid < W4) S.klen_l[tid] = kblen[(size_t)(j-1)*W4 + tid];
      }
    }
    __syncthreads();

    // ---- PROJ (h-independent): gx=x·WiT(global), awi=x·Ai(LDS), wgp=wemb·WwiT(global)
    //      128 dots, 4 passes of 32 ----
    {
      const int sub = tid & 7;
      #pragma unroll
      for (int p = 0; p < 4; ++p){
        int dotid = p*32 + (tid >> 3);
        float acc = 0.f;
        if (dotid < 24){                       // gx: coalesced global WiT rows
          int col = (dotid >> 3)*512 + base + (dotid & 7);
          const float* Wp = WiT + (size_t)col*512;
          #pragma unroll
          for (int i2 = 0; i2 < 16; ++i2){
            int cch = (i2 << 3) | sub;
            const float4 a4 = *(const float4*)&S.x_l[cch << 2];
            const float4 w4 = *(const float4*)&Wp[cch << 2];
            acc = fmaf(a4.x, w4.x, acc); acc = fmaf(a4.y, w4.y, acc);
            acc = fmaf(a4.z, w4.z, acc); acc = fmaf(a4.w, w4.w, acc);
          }
        } else if (dotid < 32){                // awi: LDS Ai
          int e = dotid - 24;
          #pragma unroll
          for (int i2 = 0; i2 < 16; ++i2){
            int cch = (i2 << 3) | sub;
            const float4 a4 = *(const float4*)&S.x_l[cch << 2];
            const float4 w4 = *(const float4*)&S.Ai_l[(e << 9) + ((cch ^ (e & 7)) << 2)];
            acc = fmaf(a4.x, w4.x, acc); acc = fmaf(a4.y, w4.y, acc);
            acc = fmaf(a4.z, w4.z, acc); acc = fmaf(a4.w, w4.w, acc);
          }
        } else {                               // wgp: coalesced global WwiT rows
          int q = dotid - 32, w = q / 24, d = q % 24;
          int col = (d >> 3)*512 + base + (d & 7);
          const float* Wp = WwiT + (size_t)col*512;
          const float* vec = &S.we_l[w*520];
          #pragma unroll
          for (int i2 = 0; i2 < 16; ++i2){
            int cch = (i2 << 3) | sub;
            const float4 a4 = *(const float4*)&vec[cch << 2];
            const float4 w4 = *(const float4*)&Wp[cch << 2];
            acc = fmaf(a4.x, w4.x, acc); acc = fmaf(a4.y, w4.y, acc);
            acc = fmaf(a4.z, w4.z, acc); acc = fmaf(a4.w, w4.w, acc);
          }
        }
        acc += __shfl_xor(acc, 1); acc += __shfl_xor(acc, 2); acc += __shfl_xor(acc, 4);
        if (sub == 0){
          if (dotid < 24)      S.gx_l[dotid]     = acc + S.bmi_l[dotid];
          else if (dotid < 32) S.awi_l[dotid-24] = acc + S.bal_l[dotid-24];
          else { int q = dotid-32; S.wgp_l[q/24][q%24] = acc + S.bw_l[q%24]; }
        }
      }
    }

    // ---- detect h(j-1) published (C-counter of step j-1); read it ----
    if (j > 0){
      if (tid == 192) detect(&cnt[2*j - 1]);
      __syncthreads();
      ((unsigned long long*)S.h_l)[tid] = ld_relax8((const unsigned long long*)hbuf + tid);
    }
    __syncthreads();

    // ---- Phase A1: wgh(j-1) = h·Wwh cols (24 dots, tid<192) ----
    if (j > 0 && tid < 192){
      const int sub = tid & 7;
      int d = tid >> 3;
      float acc = 0.f;
      #pragma unroll
      for (int i2 = 0; i2 < 16; ++i2){
        int cch = (i2 << 3) | sub;
        const float4 hv  = *(const float4*)&S.h_l[cch << 2];
        const float4 wv4 = *(const float4*)&S.Wwh_l[(d << 9) + ((cch ^ (d & 7)) << 2)];
        acc = fmaf(hv.x, wv4.x, acc); acc = fmaf(hv.y, wv4.y, acc);
        acc = fmaf(hv.z, wv4.z, acc); acc = fmaf(hv.w, wv4.w, acc);
      }
      acc += __shfl_xor(acc, 1); acc += __shfl_xor(acc, 2); acc += __shfl_xor(acc, 4);
      if (sub == 0) S.wgh_l[d] = acc;
    }
    __syncthreads();

    if (j > 0){
      // ---- wc(j-1) local slice, publish; flat-arrive (A-counter, step j) ----
      if (tid < W4*HS){
        int w = tid >> 3, e = tid & 7;
        float fr = S.wgp_l[w][e]    + S.wgh_l[e];
        float ir = S.wgp_l[w][8+e]  + S.wgh_l[8+e];
        float gr = S.wgp_l[w][16+e] + S.wgh_l[16+e];
        float wcv = sigf(fr)*S.c_prev_l[e] + sigf(ir)*tanhft(gr);
        st_relax(&wcbuf[w*H + base + e], wcv);
      }
      __syncthreads();               // drain wc stores
      if (tid == 192) arrive(&cnt[2*j]);
    }

    // ---- Phase A2: gh(j) = h·Wh cols (24 dots, tid<192) — hides A-barrier ----
    if (tid < 192){
      const int sub = tid & 7;
      int d = tid >> 3;
      float acc = 0.f;
      #pragma unroll
      for (int i2 = 0; i2 < 16; ++i2){
        int cch = (i2 << 3) | sub;
        const float4 hv  = *(const float4*)&S.h_l[cch << 2];
        const float4 wv4 = *(const float4*)&S.Wh_l[(d << 9) + ((cch ^ (d & 7)) << 2)];
        acc = fmaf(hv.x, wv4.x, acc); acc = fmaf(hv.y, wv4.y, acc);
        acc = fmaf(hv.z, wv4.z, acc); acc = fmaf(hv.w, wv4.w, acc);
      }
      acc += __shfl_xor(acc, 1); acc += __shfl_xor(acc, 2); acc += __shfl_xor(acc, 4);
      if (sub == 0) S.gh_l[d] = acc;
    }

    // ---- detect A-counter; read full wc(j-1) ----
    if (j > 0){
      if (tid == 192) detect(&cnt[2*j]);
      __syncthreads();
      const unsigned long long* wb = (const unsigned long long*)wcbuf;
      #pragma unroll
      for (int r = 0; r < 4; ++r){
        int i = r*NTH + tid;                       // pair index 0..1023
        unsigned long long v = ld_relax8(&wb[i]);
        int w = i >> 8, k = (i & 255) << 1;
        *(unsigned long long*)&S.wcf[w*520 + k] = v;
      }
    }
    __syncthreads();

    // ---- Phase B: awh(j-1) slice = wc·Ah cols (32 dots, all 256); ring update ----
    if (j > 0){
      const int s = (j-1) & 7;
      {
        int dt = tid >> 3, sub = tid & 7;
        int w = dt >> 3, c = dt & 7;
        float acc = 0.f;
        #pragma unroll
        for (int i2 = 0; i2 < 16; ++i2){
          int cch = (i2 << 3) | sub;
          const float4 wv4 = *(const float4*)&S.wcf[w*520 + (cch << 2)];
          const float4 av  = *(const float4*)&S.Ah_l[(c << 9) + ((cch ^ (c & 7)) << 2)];
          acc = fmaf(wv4.x, av.x, acc); acc = fmaf(wv4.y, av.y, acc);
          acc = fmaf(wv4.z, av.z, acc); acc = fmaf(wv4.w, av.w, acc);
        }
        acc += __shfl_xor(acc, 1); acc += __shfl_xor(acc, 2); acc += __shfl_xor(acc, 4);
        if (sub == 0) S.ring_awh_l[s][w][c] = acc;
      }
      if (tid < W4*HS){ int w = tid >> 3, e = tid & 7; S.ring_c_l[s][w][e] = S.wcf[w*520 + base + e]; }
      if (tid < W4) S.ring_len_l[s][tid] = S.klen_l[tid];
      if (tid == 0) S.ring_step_l[s] = j-1;
    }
    __syncthreads();

    // ---- Phase C: part2(j) — 32 entries x 8 elems = 256 threads ----
    {
      int entry = tid & 31, e = tid >> 5;
      int s = entry >> 2, w = entry & 3;
      bool msk = (S.ring_step_l[s] + S.ring_len_l[s][w] - 1 == j);
      float aw = S.awi_l[e] + S.ring_awh_l[s][w][e];
      float ev  = msk ? __expf(sigf(aw)) : 0.f;
      float ecv = msk ? ev * S.ring_c_l[s][w][e] : 0.f;
      #pragma unroll
      for (int m = 1; m < 32; m <<= 1){
        ev  += __shfl_xor(ev,  m);
        ecv += __shfl_xor(ecv, m);
      }
      int anym = __any((int)msk);
      float ir  = S.gx_l[e]    + S.gh_l[e];
      float orr = S.gx_l[8+e]  + S.gh_l[8+e];
      float gr  = S.gx_l[16+e] + S.gh_l[16+e];
      float i_g = sigf(ir), o_g = tanhft(orr), g_g = sigf(gr);
      float e_i = __expf(i_g);
      float c_new;
      if (anym) c_new = (e_i*g_g + ecv) / (e_i + ev);
      else      c_new = (1.f - i_g)*S.c_prev_l[e] + i_g*g_g;
      float h_new = o_g * tanhft(c_new);
      if (entry == 0){
        st_relax(&hbuf[base+e], h_new);
        // out[] via relaxed agent atomics: no dirty L2 lines for release-wb
        st_relax(&out[(size_t)j*H + base + e], h_new);
        st_relax(&out[(size_t)T*H + (size_t)j*H + base + e], c_new);
        S.c_prev_l[e] = c_new;
      }
    }
    __syncthreads();                 // drain h stores
    if (tid == 192) arrive(&cnt[2*j + 1]);   // C-counter of step j; detected next step
  }
}

// ---------- launcher ----------
extern "C" void kernel_launch(void* const* d_in, const int* in_sizes, int n_in,
                              void* d_out, int out_size, void* d_ws, size_t ws_size,
                              hipStream_t stream)
{
  const float* x    = (const float*)d_in[0];
  const float* kbe  = (const float*)d_in[1];
  const int*   kblen= (const int*)d_in[2];
  const float* Wi   = (const float*)d_in[3];
  const float* Wh   = (const float*)d_in[4];
  const float* bmi  = (const float*)d_in[5];
  const float* Ai   = (const float*)d_in[6];
  const float* Ah   = (const float*)d_in[7];
  const float* bal  = (const float*)d_in[8];
  const float* Wwi  = (const float*)d_in[9];
  const float* Wwh  = (const float*)d_in[10];
  const float* bw   = (const float*)d_in[11];
  const int T = in_sizes[0] / H;     // 1024
  float* out = (float*)d_out;        // reference output dtype = float32

  // workspace: WiT[1536*512] | WwiT[1536*512] | hbuf[512] | wcbuf[2048] | cnt[2*T]
  float* ws    = (float*)d_ws;
  float* WiT   = ws;
  float* WwiT  = WiT + (size_t)1536*512;
  float* hbuf  = WwiT + (size_t)1536*512;
  float* wcbuf = hbuf + 512;
  int*   cnt   = (int*)(wcbuf + 2048);

  (void)hipMemsetAsync(cnt, 0, (size_t)2*T*sizeof(int), stream);

  transpose_k<<<dim3(48,16), 256, 0, stream>>>(Wi,  WiT);
  transpose_k<<<dim3(48,16), 256, 0, stream>>>(Wwi, WwiT);

  lattice_serial<<<NWG, NTH, 0, stream>>>(x, kbe, kblen, WiT, Wh, bmi, Ai, Ah, bal,
                                          WwiT, Wwh, bw, hbuf, wcbuf, cnt, out, T);
}

// Round 20
// 12641.611 us; speedup vs baseline: 1.9215x; 1.0226x over previous
//
#include <hip/hip_runtime.h>

#define H 512
#define W4 4
#define RINGN 8
#define NWG 64
#define HS 8          // H / NWG
#define NTH 256

// ---------- helpers ----------
__device__ __forceinline__ float sigf(float x){ return 1.f/(1.f+__expf(-x)); }
__device__ __forceinline__ float tanhft(float x){
  float t = __expf(-2.f*fabsf(x));      // never overflows
  float r = (1.f - t)/(1.f + t);
  return copysignf(r, x);
}
// swizzled LDS element index for column-major weight slices
__device__ __forceinline__ int swz(int dd, int k){
  return (dd << 9) | ((((k >> 2) ^ (dd & 7)) << 2) | (k & 3));
}
__device__ __forceinline__ void st_relax(float* p, float v){
  __hip_atomic_store(p, v, __ATOMIC_RELAXED, __HIP_MEMORY_SCOPE_AGENT);
}
__device__ __forceinline__ unsigned long long ld_relax8(const unsigned long long* p){
  return __hip_atomic_load(p, __ATOMIC_RELAXED, __HIP_MEMORY_SCOPE_AGENT);
}
// per-producer tag protocol: producer stores data (relaxed) -> __syncthreads
// (vmcnt drain: data acked at IC) -> ONE release tag store to its own line.
// Consumers: 64 threads each poll one distinct tag line (relaxed, acquire
// fallback every 256 iters), then __syncthreads, then gather data arrays.
__device__ __forceinline__ void poll_tag(const int* t, int target){
  int it = 0;
  while (1){
    int v = ((++it & 255) == 0)
      ? __hip_atomic_load(t, __ATOMIC_ACQUIRE, __HIP_MEMORY_SCOPE_AGENT)
      : __hip_atomic_load(t, __ATOMIC_RELAXED, __HIP_MEMORY_SCOPE_AGENT);
    if (v >= target) break;
    __builtin_amdgcn_s_sleep(1);
  }
}

// ---------- transpose: in[512][1536] -> out[1536][512] (both sides coalesced) ----------
__global__ __launch_bounds__(256) void transpose_k(const float* __restrict__ in,
                                                   float* __restrict__ out){
  __shared__ float tile[32][33];
  const int bx = blockIdx.x, by = blockIdx.y;
  const int tx = threadIdx.x & 31, ty = threadIdx.x >> 5;
  #pragma unroll
  for (int r = 0; r < 4; ++r)
    tile[ty + r*8][tx] = in[(size_t)(by*32 + ty + r*8)*1536 + bx*32 + tx];
  __syncthreads();
  #pragma unroll
  for (int r = 0; r < 4; ++r)
    out[(size_t)(bx*32 + ty + r*8)*512 + by*32 + tx] = tile[tx][ty + r*8];
}

// ---------- persistent serial lattice scan (NWG=64, HS=8, tagged exchange) ----------
struct SLds {
  float Wh_l [24*512];
  float Wwh_l[24*512];
  float Ah_l [8*512];
  float Ai_l [8*512];
  float h_l [H];
  float x_l [H];
  float we_l[W4*520];          // wemb(j-1) rows, padded stride
  float wcf [W4*520];          // full wc(j-1), padded stride
  float gh_l[24];
  float wgh_l[24];
  float gx_l[24];
  float awi_l[HS];
  float wgp_l[W4][24];
  float bmi_l[24];
  float bw_l [24];
  float bal_l[HS];
  float ring_c_l  [RINGN][W4][HS];
  float ring_awh_l[RINGN][W4][HS];
  float c_prev_l[HS];
  int ring_len_l[RINGN][W4];
  int ring_step_l[RINGN];
  int klen_l[W4];
};

__global__ __launch_bounds__(NTH) void lattice_serial(
    const float* __restrict__ xg,  const float* __restrict__ kbe,
    const int*   __restrict__ kblen,
    const float* __restrict__ WiT, const float* __restrict__ Wh,
    const float* __restrict__ bmi, const float* __restrict__ Ai,
    const float* __restrict__ Ah,  const float* __restrict__ bal,
    const float* __restrict__ WwiT,const float* __restrict__ Wwh,
    const float* __restrict__ bw,
    float* hbuf, float* wcbuf, int* htag, int* wctag,
    float* __restrict__ out, int T)
{
  __shared__ SLds S;
  const int tid  = threadIdx.x;
  const int wg   = blockIdx.x;
  const int base = wg * HS;

  // ---- stage weight column slices (f32, swizzled): Wh, Wwh, Ah, Ai ----
  for (int i = tid; i < 24*512; i += NTH){
    int d = i >> 9, k = i & 511;
    size_t gcol = (size_t)(d >> 3)*512 + base + (d & 7);
    S.Wh_l [swz(d,k)] = Wh [(size_t)k*1536 + gcol];
    S.Wwh_l[swz(d,k)] = Wwh[(size_t)k*1536 + gcol];
  }
  for (int i = tid; i < 8*512; i += NTH){
    int c = i >> 9, k = i & 511;
    S.Ah_l[swz(c,k)] = Ah[(size_t)k*512 + base + c];
    S.Ai_l[swz(c,k)] = Ai[(size_t)k*512 + base + c];
  }
  if (tid < 24){
    int gcol = (tid >> 3)*512 + base + (tid & 7);
    S.bmi_l[tid] = bmi[gcol];
    S.bw_l [tid] = bw [gcol];
  }
  if (tid >= 32 && tid < 32+HS) S.bal_l[tid-32] = bal[base + tid - 32];
  for (int i = tid; i < H; i += NTH){ S.h_l[i] = 0.f; S.x_l[i] = 0.f; }
  for (int i = tid; i < W4*520; i += NTH) S.we_l[i] = 0.f;
  for (int i = tid; i < RINGN*W4*HS; i += NTH){
    ((float*)S.ring_c_l)[i]   = 0.f;
    ((float*)S.ring_awh_l)[i] = 0.f;
  }
  if (tid < RINGN) S.ring_step_l[tid] = -2*RINGN;
  if (tid < RINGN*W4) ((int*)S.ring_len_l)[tid] = 0;
  if (tid < HS) S.c_prev_l[tid] = 0.f;
  __syncthreads();

  for (int j = 0; j < T; ++j){
    // ---- stage x(j), wemb(j-1), klen(j-1) (h-independent) ----
    {
      float xv0 = xg[(size_t)j*H + tid];
      float xv1 = xg[(size_t)j*H + NTH + tid];
      S.x_l[tid] = xv0; S.x_l[NTH + tid] = xv1;
      if (j > 0){
        #pragma unroll
        for (int r = 0; r < 8; ++r){
          int i = r*NTH + tid;
          S.we_l[(i >> 9)*520 + (i & 511)] = kbe[(size_t)(j-1)*(W4*H) + i];
        }
        if (tid < W4) S.klen_l[tid] = kblen[(size_t)(j-1)*W4 + tid];
      }
    }
    __syncthreads();

    // ---- PROJ (h-independent): gx=x·WiT(global), awi=x·Ai(LDS), wgp=wemb·WwiT(global)
    //      128 dots, 4 passes of 32 ----
    {
      const int sub = tid & 7;
      #pragma unroll
      for (int p = 0; p < 4; ++p){
        int dotid = p*32 + (tid >> 3);
        float acc = 0.f;
        if (dotid < 24){                       // gx: coalesced global WiT rows
          int col = (dotid >> 3)*512 + base + (dotid & 7);
          const float* Wp = WiT + (size_t)col*512;
          #pragma unroll
          for (int i2 = 0; i2 < 16; ++i2){
            int cch = (i2 << 3) | sub;
            const float4 a4 = *(const float4*)&S.x_l[cch << 2];
            const float4 w4 = *(const float4*)&Wp[cch << 2];
            acc = fmaf(a4.x, w4.x, acc); acc = fmaf(a4.y, w4.y, acc);
            acc = fmaf(a4.z, w4.z, acc); acc = fmaf(a4.w, w4.w, acc);
          }
        } else if (dotid < 32){                // awi: LDS Ai
          int e = dotid - 24;
          #pragma unroll
          for (int i2 = 0; i2 < 16; ++i2){
            int cch = (i2 << 3) | sub;
            const float4 a4 = *(const float4*)&S.x_l[cch << 2];
            const float4 w4 = *(const float4*)&S.Ai_l[(e << 9) + ((cch ^ (e & 7)) << 2)];
            acc = fmaf(a4.x, w4.x, acc); acc = fmaf(a4.y, w4.y, acc);
            acc = fmaf(a4.z, w4.z, acc); acc = fmaf(a4.w, w4.w, acc);
          }
        } else {                               // wgp: coalesced global WwiT rows
          int q = dotid - 32, w = q / 24, d = q % 24;
          int col = (d >> 3)*512 + base + (d & 7);
          const float* Wp = WwiT + (size_t)col*512;
          const float* vec = &S.we_l[w*520];
          #pragma unroll
          for (int i2 = 0; i2 < 16; ++i2){
            int cch = (i2 << 3) | sub;
            const float4 a4 = *(const float4*)&vec[cch << 2];
            const float4 w4 = *(const float4*)&Wp[cch << 2];
            acc = fmaf(a4.x, w4.x, acc); acc = fmaf(a4.y, w4.y, acc);
            acc = fmaf(a4.z, w4.z, acc); acc = fmaf(a4.w, w4.w, acc);
          }
        }
        acc += __shfl_xor(acc, 1); acc += __shfl_xor(acc, 2); acc += __shfl_xor(acc, 4);
        if (sub == 0){
          if (dotid < 24)      S.gx_l[dotid]     = acc + S.bmi_l[dotid];
          else if (dotid < 32) S.awi_l[dotid-24] = acc + S.bal_l[dotid-24];
          else { int q = dotid-32; S.wgp_l[q/24][q%24] = acc + S.bw_l[q%24]; }
        }
      }
    }

    // ---- poll h-tags (h(j-1) published with tag j); gather hbuf ----
    if (j > 0){
      if (tid < NWG) poll_tag(&htag[tid*32], j);
      __syncthreads();
      ((unsigned long long*)S.h_l)[tid] = ld_relax8((const unsigned long long*)hbuf + tid);
    }
    __syncthreads();

    // ---- Phase A1: wgh(j-1) = h·Wwh cols (24 dots, tid<192) ----
    if (j > 0 && tid < 192){
      const int sub = tid & 7;
      int d = tid >> 3;
      float acc = 0.f;
      #pragma unroll
      for (int i2 = 0; i2 < 16; ++i2){
        int cch = (i2 << 3) | sub;
        const float4 hv  = *(const float4*)&S.h_l[cch << 2];
        const float4 wv4 = *(const float4*)&S.Wwh_l[(d << 9) + ((cch ^ (d & 7)) << 2)];
        acc = fmaf(hv.x, wv4.x, acc); acc = fmaf(hv.y, wv4.y, acc);
        acc = fmaf(hv.z, wv4.z, acc); acc = fmaf(hv.w, wv4.w, acc);
      }
      acc += __shfl_xor(acc, 1); acc += __shfl_xor(acc, 2); acc += __shfl_xor(acc, 4);
      if (sub == 0) S.wgh_l[d] = acc;
    }
    __syncthreads();

    if (j > 0){
      // ---- wc(j-1) local slice, publish; release own wc-tag ----
      if (tid < W4*HS){
        int w = tid >> 3, e = tid & 7;
        float fr = S.wgp_l[w][e]    + S.wgh_l[e];
        float ir = S.wgp_l[w][8+e]  + S.wgh_l[8+e];
        float gr = S.wgp_l[w][16+e] + S.wgh_l[16+e];
        float wcv = sigf(fr)*S.c_prev_l[e] + sigf(ir)*tanhft(gr);
        st_relax(&wcbuf[w*H + base + e], wcv);
      }
      __syncthreads();               // drain wc stores to IC
      if (tid == 192)
        __hip_atomic_store(&wctag[wg*32], j, __ATOMIC_RELEASE, __HIP_MEMORY_SCOPE_AGENT);
    }

    // ---- Phase A2: gh(j) = h·Wh cols (24 dots, tid<192) — hides wc-tag latency ----
    if (tid < 192){
      const int sub = tid & 7;
      int d = tid >> 3;
      float acc = 0.f;
      #pragma unroll
      for (int i2 = 0; i2 < 16; ++i2){
        int cch = (i2 << 3) | sub;
        const float4 hv  = *(const float4*)&S.h_l[cch << 2];
        const float4 wv4 = *(const float4*)&S.Wh_l[(d << 9) + ((cch ^ (d & 7)) << 2)];
        acc = fmaf(hv.x, wv4.x, acc); acc = fmaf(hv.y, wv4.y, acc);
        acc = fmaf(hv.z, wv4.z, acc); acc = fmaf(hv.w, wv4.w, acc);
      }
      acc += __shfl_xor(acc, 1); acc += __shfl_xor(acc, 2); acc += __shfl_xor(acc, 4);
      if (sub == 0) S.gh_l[d] = acc;
    }

    // ---- poll wc-tags; gather full wc(j-1) ----
    if (j > 0){
      if (tid < NWG) poll_tag(&wctag[tid*32], j);
      __syncthreads();
      const unsigned long long* wb = (const unsigned long long*)wcbuf;
      #pragma unroll
      for (int r = 0; r < 4; ++r){
        int i = r*NTH + tid;                       // pair index 0..1023
        unsigned long long v = ld_relax8(&wb[i]);
        int w = i >> 8, k = (i & 255) << 1;
        *(unsigned long long*)&S.wcf[w*520 + k] = v;
      }
    }
    __syncthreads();

    // ---- Phase B: awh(j-1) slice = wc·Ah cols (32 dots, all 256); ring update ----
    if (j > 0){
      const int s = (j-1) & 7;
      {
        int dt = tid >> 3, sub = tid & 7;
        int w = dt >> 3, c = dt & 7;
        float acc = 0.f;
        #pragma unroll
        for (int i2 = 0; i2 < 16; ++i2){
          int cch = (i2 << 3) | sub;
          const float4 wv4 = *(const float4*)&S.wcf[w*520 + (cch << 2)];
          const float4 av  = *(const float4*)&S.Ah_l[(c << 9) + ((cch ^ (c & 7)) << 2)];
          acc = fmaf(wv4.x, av.x, acc); acc = fmaf(wv4.y, av.y, acc);
          acc = fmaf(wv4.z, av.z, acc); acc = fmaf(wv4.w, av.w, acc);
        }
        acc += __shfl_xor(acc, 1); acc += __shfl_xor(acc, 2); acc += __shfl_xor(acc, 4);
        if (sub == 0) S.ring_awh_l[s][w][c] = acc;
      }
      if (tid < W4*HS){ int w = tid >> 3, e = tid & 7; S.ring_c_l[s][w][e] = S.wcf[w*520 + base + e]; }
      if (tid < W4) S.ring_len_l[s][tid] = S.klen_l[tid];
      if (tid == 0) S.ring_step_l[s] = j-1;
    }
    __syncthreads();

    // ---- Phase C: part2(j) — 32 entries x 8 elems = 256 threads ----
    {
      int entry = tid & 31, e = tid >> 5;
      int s = entry >> 2, w = entry & 3;
      bool msk = (S.ring_step_l[s] + S.ring_len_l[s][w] - 1 == j);
      float aw = S.awi_l[e] + S.ring_awh_l[s][w][e];
      float ev  = msk ? __expf(sigf(aw)) : 0.f;
      float ecv = msk ? ev * S.ring_c_l[s][w][e] : 0.f;
      #pragma unroll
      for (int m = 1; m < 32; m <<= 1){
        ev  += __shfl_xor(ev,  m);
        ecv += __shfl_xor(ecv, m);
      }
      int anym = __any((int)msk);
      float ir  = S.gx_l[e]    + S.gh_l[e];
      float orr = S.gx_l[8+e]  + S.gh_l[8+e];
      float gr  = S.gx_l[16+e] + S.gh_l[16+e];
      float i_g = sigf(ir), o_g = tanhft(orr), g_g = sigf(gr);
      float e_i = __expf(i_g);
      float c_new;
      if (anym) c_new = (e_i*g_g + ecv) / (e_i + ev);
      else      c_new = (1.f - i_g)*S.c_prev_l[e] + i_g*g_g;
      float h_new = o_g * tanhft(c_new);
      if (entry == 0){
        st_relax(&hbuf[base+e], h_new);
        st_relax(&out[(size_t)j*H + base + e], h_new);
        st_relax(&out[(size_t)T*H + (size_t)j*H + base + e], c_new);
        S.c_prev_l[e] = c_new;
      }
    }
    __syncthreads();                 // drain h stores to IC
    if (tid == 192)                  // release own h-tag (value j+1)
      __hip_atomic_store(&htag[wg*32], j+1, __ATOMIC_RELEASE, __HIP_MEMORY_SCOPE_AGENT);
  }
}

// ---------- launcher ----------
extern "C" void kernel_launch(void* const* d_in, const int* in_sizes, int n_in,
                              void* d_out, int out_size, void* d_ws, size_t ws_size,
                              hipStream_t stream)
{
  const float* x    = (const float*)d_in[0];
  const float* kbe  = (const float*)d_in[1];
  const int*   kblen= (const int*)d_in[2];
  const float* Wi   = (const float*)d_in[3];
  const float* Wh   = (const float*)d_in[4];
  const float* bmi  = (const float*)d_in[5];
  const float* Ai   = (const float*)d_in[6];
  const float* Ah   = (const float*)d_in[7];
  const float* bal  = (const float*)d_in[8];
  const float* Wwi  = (const float*)d_in[9];
  const float* Wwh  = (const float*)d_in[10];
  const float* bw   = (const float*)d_in[11];
  const int T = in_sizes[0] / H;     // 1024
  float* out = (float*)d_out;        // reference output dtype = float32

  // workspace: WiT | WwiT | hbuf[512] | wcbuf[2048] | htag[64*32] | wctag[64*32]
  float* ws    = (float*)d_ws;
  float* WiT   = ws;
  float* WwiT  = WiT + (size_t)1536*512;
  float* hbuf  = WwiT + (size_t)1536*512;
  float* wcbuf = hbuf + 512;
  int*   htag  = (int*)(wcbuf + 2048);
  int*   wctag = htag + NWG*32;

  (void)hipMemsetAsync(htag, 0, (size_t)2*NWG*32*sizeof(int), stream);

  transpose_k<<<dim3(48,16), 256, 0, stream>>>(Wi,  WiT);
  transpose_k<<<dim3(48,16), 256, 0, stream>>>(Wwi, WwiT);

  lattice_serial<<<NWG, NTH, 0, stream>>>(x, kbe, kblen, WiT, Wh, bmi, Ai, Ah, bal,
                                          WwiT, Wwh, bw, hbuf, wcbuf, htag, wctag, out, T);
}